// Round 23
// baseline (474.258 us; speedup 1.0000x reference)
//
#include <hip/hip_runtime.h>
#include <hip/hip_bf16.h>
#include <math.h>

typedef __bf16 bf16;
typedef __bf16 bf16x8 __attribute__((ext_vector_type(8)));
typedef float f32x4 __attribute__((ext_vector_type(4)));

#define AS1(p) ((const __attribute__((address_space(1))) void*)(p))
#define AS3(p) ((__attribute__((address_space(3))) void*)(p))

__device__ __forceinline__ void gl_lds16(const bf16* g, bf16* l) {
    __builtin_amdgcn_global_load_lds(AS1(g), AS3(l), 16, 0, 0);
}

// ---------------- fused prep: cast x, transpose+cast wqkv, transpose+cast wproj -------
__device__ __forceinline__ void transpose_body(const float* __restrict__ in,
                                               bf16* __restrict__ out,
                                               int R, int Cc, int bx, int by, int t) {
    __shared__ float tile[32][33];
    const int r0 = by * 32, c0 = bx * 32;
    for (int i = 0; i < 4; ++i) {
        int idx = t + i * 256;
        int r = idx >> 5, c = idx & 31;
        tile[r][c] = in[(size_t)(r0 + r) * Cc + c0 + c];
    }
    __syncthreads();
    for (int i = 0; i < 4; ++i) {
        int idx = t + i * 256;
        int r = idx >> 5, c = idx & 31;
        out[(size_t)(c0 + r) * R + r0 + c] = (bf16)tile[c][r];
    }
}

__global__ __launch_bounds__(256) void prep_all(const float* __restrict__ x, bf16* __restrict__ xb,
                                                const float* __restrict__ wqkv, bf16* __restrict__ wqkvT,
                                                const float* __restrict__ wproj, bf16* __restrict__ wprojT) {
    const int t = threadIdx.x;
    const int bid = blockIdx.x;
    if (bid < 16384) {
        long i = ((long)bid * 256 + t) * 4;
        float4 v = *(const float4*)(x + i);
        xb[i + 0] = (bf16)v.x;
        xb[i + 1] = (bf16)v.y;
        xb[i + 2] = (bf16)v.z;
        xb[i + 3] = (bf16)v.w;
    } else if (bid < 28672) {
        int idx = bid - 16384;                       // 192 x 64 tiles
        transpose_body(wqkv, wqkvT, 2048, 6144, idx % 192, idx / 192, t);
    } else {
        int idx = bid - 28672;                       // 64 x 64 tiles
        transpose_body(wproj, wprojT, 2048, 2048, idx % 64, idx / 64, t);
    }
}

// ---------------- GEMM 256x256, BK=32, 16 waves (4x4), double-buffered LDS -----------
// Round-20 template with BK=64->32 and launch_bounds(1024,4) KEPT (round-21's spill
// was the (1024,8) 64-reg cap, NOT BK=32): LDS 128->64KB -> 2 blocks/CU; VGPR ~56
// <= 64 -> hardware schedules 8 waves/SIMD naturally (32 waves/CU). Cross-block
// waves are not barrier-locked to each other -> they cover the per-iter barrier
// drain and LDS bursts (m114 mechanism; r16 proved 2->4 waves/SIMD = +6%).
// BK=32 swizzle chunk ^ ((row>>1)&3): ran with 0 bank conflicts in round 9.
// bn-supertile order (nbx % 8 == 0).
template <typename OT>
__global__ __launch_bounds__(1024, 4) void gemm256_bt(const bf16* __restrict__ A,
                                                      const bf16* __restrict__ BT,
                                                      OT* __restrict__ C,
                                                      int M, int N, int K) {
    __shared__ bf16 lds[2][2][256 * 32];  // [buf][A/B][row*32 + col] = 64 KB total
    const int t = threadIdx.x;
    const int lane = t & 63;
    const int w = t >> 6;
    const int wr = w >> 2, wc = w & 3;      // 4 x 4 wave grid; wave out = 64x64
    const int l15 = lane & 15, lg = lane >> 4;

    // supertile remap: 8 consecutive bn columns x all bm per group
    const int nbx = gridDim.x, nby = gridDim.y;
    const int orig = blockIdx.y * nbx + blockIdx.x;
    const int span = nby * 8;
    const int grp = orig / span, rem = orig % span;
    const int bm = rem >> 3, bn = grp * 8 + (rem & 7);

    const bf16* Ab = A + (size_t)bm * 256 * K;
    const bf16* Bb = BT + (size_t)bn * 256 * K;

    f32x4 acc[4][4] = {};

    const int nk = K / 32;
    int cur = 0;
    // prologue: stage K-tile 0 into buf0 (1024 chunks of 16B per operand, 1/thread)
    {
        int r = t >> 2, c = t & 3;
        int src = (c ^ ((r >> 1) & 3)) << 3;
        gl_lds16(Ab + (size_t)r * K + src, &lds[0][0][t * 8]);
        gl_lds16(Bb + (size_t)r * K + src, &lds[0][1][t * 8]);
    }

    for (int kt = 0; kt < nk; ++kt) {
        __syncthreads();  // buf[cur] staged loads landed; all prior ds_reads complete

        if (kt + 1 < nk) {  // issue prefetch AFTER barrier -> flies a full iteration
            const int k0 = (kt + 1) * 32;
            int r = t >> 2, c = t & 3;
            int src = (c ^ ((r >> 1) & 3)) << 3;
            gl_lds16(Ab + (size_t)r * K + k0 + src, &lds[cur ^ 1][0][t * 8]);
            gl_lds16(Bb + (size_t)r * K + k0 + src, &lds[cur ^ 1][1][t * 8]);
        }

        const bf16* lA = &lds[cur][0][0];
        const bf16* lB = &lds[cur][1][0];
        bf16x8 bfr[4];
        #pragma unroll
        for (int n = 0; n < 4; ++n) {
            int R = wc * 64 + n * 16 + l15;
            bfr[n] = *(const bf16x8*)(lB + R * 32 + ((lg ^ ((R >> 1) & 3)) << 3));
        }
        // software-pipelined A reads: issue m+1's read during m's MFMAs
        int R0 = wr * 64 + l15;
        bf16x8 a = *(const bf16x8*)(lA + R0 * 32 + ((lg ^ ((R0 >> 1) & 3)) << 3));
        __builtin_amdgcn_s_setprio(1);
        #pragma unroll
        for (int m = 0; m < 4; ++m) {
            bf16x8 c0 = a;
            if (m + 1 < 4) {
                int Rn = wr * 64 + (m + 1) * 16 + l15;
                a = *(const bf16x8*)(lA + Rn * 32 + ((lg ^ ((Rn >> 1) & 3)) << 3));
            }
            #pragma unroll
            for (int n = 0; n < 4; ++n)
                acc[m][n] = __builtin_amdgcn_mfma_f32_16x16x32_bf16(c0, bfr[n], acc[m][n], 0, 0, 0);
        }
        __builtin_amdgcn_s_setprio(0);
        cur ^= 1;
    }

    for (int m = 0; m < 4; ++m)
        for (int n = 0; n < 4; ++n) {
            int row = bm * 256 + wr * 64 + m * 16 + lg * 4;
            int col = bn * 256 + wc * 64 + n * 16 + l15;
            for (int r = 0; r < 4; ++r)
                C[(size_t)(row + r) * N + col] = (OT)acc[m][n][r];
        }
}

// ---------------- causal flash attention ----------------
// Round-20 config (best): single-buffered lK (3 blocks/CU), early V(t+1)->regs at
// top of tile, K(t+1) gl_lds after barrier B. lK/lVt XOR-chunk-swizzled; lP stride
// 68; exp2-domain softmax, defer-max, Q-prescaled, causal fast-path, balanced pairs.
__global__ __launch_bounds__(256, 2) void attn_fwd(const bf16* __restrict__ QKV,
                                                   bf16* __restrict__ O) {
    __shared__ bf16 lK[64 * 128];    // [64 kv][16 chunks of 8], chunk ^ (row&7)
    __shared__ bf16 lVt[128 * 64];   // V^T [128 hd][8 chunks of 8], chunk ^ (row&7)
    __shared__ bf16 lP[4][32 * 68];  // per-wave P [32 q][64 kv], row stride 68

    const int t = threadIdx.x, lane = t & 63, w = t >> 6;
    const int l15 = lane & 15, lg = lane >> 4;
    const int bh = blockIdx.y;
    const int b = bh >> 4, h = bh & 15;
    const size_t rs = 6144;

    const bf16* Qb = QKV + (size_t)b * 2048 * rs + h * 128;
    const bf16* Kb = Qb + 2048;
    const bf16* Vb = Qb + 4096;

    const float C = 0.12751705f;  // 128^-0.5 * log2(e)
    const int kvp = t & 31;         // kv-pair id for V staging
    const int hd0 = (t >> 5) * 16;  // hd group base for V staging

    for (int half = 0; half < 2; ++half) {
        const int qt = half == 0 ? (15 - (int)blockIdx.x) : (int)blockIdx.x;
        const int q0 = qt * 128;
        const int qa = q0 + w * 32;  // wave's q rows [qa, qa+32)

        // Q fragments, PRESCALED by C (exp2-domain)
        bf16x8 qf[2][4];
        for (int f = 0; f < 2; ++f)
            for (int kk = 0; kk < 4; ++kk) {
                bf16x8 q = *(const bf16x8*)(Qb + (size_t)(qa + f * 16 + l15) * rs + kk * 32 + lg * 8);
                for (int e = 0; e < 8; ++e) q[e] = (bf16)((float)q[e] * C);
                qf[f][kk] = q;
            }

        f32x4 o[2][8] = {};
        float m2[2][4], l2[2][4];
        for (int f = 0; f < 2; ++f)
            for (int r = 0; r < 4; ++r) { m2[f][r] = -1e30f; l2[f][r] = 0.f; }

        const int nt = q0 / 64 + 2;

        // prologue: stage K(0) via gl_lds, V(0) -> regs
        for (int j = 0; j < 4; ++j) {
            int c = j * 256 + t;
            int r = c >> 4, cc = c & 15;
            gl_lds16(Kb + (size_t)r * rs + ((cc ^ (r & 7)) << 3), lK + (size_t)c * 8);
        }
        bf16x8 vr0, vr1, vr2, vr3;
        {
            const bf16* p = Vb + (size_t)(2 * kvp) * rs + hd0;
            vr0 = *(const bf16x8*)(p);
            vr1 = *(const bf16x8*)(p + rs);
            vr2 = *(const bf16x8*)(p + 8);
            vr3 = *(const bf16x8*)(p + rs + 8);
        }

        for (int kt = 0; kt < nt; ++kt) {
            const int kv0 = kt * 64;
            __syncthreads();  // barrier A: drains vmcnt -> K(kt) in LDS, V(kt) in regs

            // write V^T (swizzled chunks), packed u32 -- frees vr0-3
            for (int e = 0; e < 8; ++e) {
                union { bf16 h2[2]; unsigned u; } p0, p1;
                p0.h2[0] = vr0[e]; p0.h2[1] = vr1[e];
                p1.h2[0] = vr2[e]; p1.h2[1] = vr3[e];
                int r0 = hd0 + e, r1 = hd0 + 8 + e;
                *(unsigned*)(lVt + r0 * 64 + (((kvp >> 2) ^ (r0 & 7)) << 3) + ((kvp & 3) << 1)) = p0.u;
                *(unsigned*)(lVt + r1 * 64 + (((kvp >> 2) ^ (r1 & 7)) << 3) + ((kvp & 3) << 1)) = p1.u;
            }

            // EARLY V(t+1)->regs: zero LDS cost, flies the whole tile (L3 latency cover)
            if (kt + 1 < nt) {
                const bf16* p = Vb + (size_t)(kv0 + 64 + 2 * kvp) * rs + hd0;
                vr0 = *(const bf16x8*)(p);
                vr1 = *(const bf16x8*)(p + rs);
                vr2 = *(const bf16x8*)(p + 8);
                vr3 = *(const bf16x8*)(p + rs + 8);
            }

            // S = Q K^T  (32 q x 64 kv); K frags reused for both q-frags
            f32x4 s[2][4] = {};
            __builtin_amdgcn_s_setprio(1);
            for (int n = 0; n < 4; ++n) {
                int row = n * 16 + l15;
                for (int kk = 0; kk < 4; ++kk) {
                    bf16x8 kf = *(const bf16x8*)(lK + row * 128 + (((kk * 4 + lg) ^ (row & 7)) << 3));
                    s[0][n] = __builtin_amdgcn_mfma_f32_16x16x32_bf16(qf[0][kk], kf, s[0][n], 0, 0, 0);
                    s[1][n] = __builtin_amdgcn_mfma_f32_16x16x32_bf16(qf[1][kk], kf, s[1][n], 0, 0, 0);
                }
            }
            __builtin_amdgcn_s_setprio(0);

            // causal mask (wave-uniform fast path: tile fully below diagonal)
            float pv[2][4][4];
            if (kv0 + 63 <= qa) {
                for (int f = 0; f < 2; ++f)
                    for (int n = 0; n < 4; ++n)
                        for (int r = 0; r < 4; ++r)
                            pv[f][n][r] = s[f][n][r];
            } else {
                for (int f = 0; f < 2; ++f)
                    for (int n = 0; n < 4; ++n)
                        for (int r = 0; r < 4; ++r) {
                            int qg = qa + f * 16 + lg * 4 + r;
                            int kg = kv0 + n * 16 + l15;
                            pv[f][n][r] = (kg <= qg) ? s[f][n][r] : -1e30f;
                        }
            }
            float pmax[2][4];
            for (int f = 0; f < 2; ++f)
                for (int r = 0; r < 4; ++r)
                    pmax[f][r] = fmaxf(fmaxf(pv[f][0][r], pv[f][1][r]), fmaxf(pv[f][2][r], pv[f][3][r]));
            for (int d = 1; d < 16; d <<= 1)
                for (int f = 0; f < 2; ++f)
                    for (int r = 0; r < 4; ++r)
                        pmax[f][r] = fmaxf(pmax[f][r], __shfl_xor(pmax[f][r], d));
            // defer-max: only rescale when max grew by > 8 (log2 domain)
            bool need = false;
            for (int f = 0; f < 2; ++f)
                for (int r = 0; r < 4; ++r)
                    need = need || (pmax[f][r] > m2[f][r] + 8.f);
            if (__any(need ? 1 : 0)) {
                for (int f = 0; f < 2; ++f)
                    for (int r = 0; r < 4; ++r) {
                        float mn = fmaxf(m2[f][r], pmax[f][r]);
                        float al = exp2f(m2[f][r] - mn);
                        m2[f][r] = mn;
                        l2[f][r] *= al;
                        for (int j = 0; j < 8; ++j) o[f][j][r] *= al;
                    }
            }
            for (int f = 0; f < 2; ++f)
                for (int n = 0; n < 4; ++n)
                    for (int r = 0; r < 4; ++r) {
                        float p = exp2f(pv[f][n][r] - m2[f][r]);
                        l2[f][r] += p;
                        lP[w][(f * 16 + lg * 4 + r) * 68 + n * 16 + l15] = (bf16)p;
                    }
            bf16x8 pf[2][2];
            for (int f = 0; f < 2; ++f) {
                pf[f][0] = *(const bf16x8*)(&lP[w][(f * 16 + l15) * 68 + lg * 8]);
                pf[f][1] = *(const bf16x8*)(&lP[w][(f * 16 + l15) * 68 + 32 + lg * 8]);
            }

            __syncthreads();  // barrier B: lVt fully written; lK reads done by all waves

            // K(t+1) -> lK via gl_lds (after barrier B: all lK reads done); flies during PV
            if (kt + 1 < nt) {
                const int nk2 = kv0 + 64;
                for (int j = 0; j < 4; ++j) {
                    int c = j * 256 + t;
                    int r = c >> 4, cc = c & 15;
                    gl_lds16(Kb + (size_t)(nk2 + r) * rs + ((cc ^ (r & 7)) << 3), lK + (size_t)c * 8);
                }
            }

            // O += P V ; V frags reused for both q-frags
            __builtin_amdgcn_s_setprio(1);
            for (int j = 0; j < 8; ++j) {
                int R = j * 16 + l15;
                bf16x8 vfa = *(const bf16x8*)(lVt + R * 64 + ((lg ^ (R & 7)) << 3));
                bf16x8 vfb = *(const bf16x8*)(lVt + R * 64 + (((4 + lg) ^ (R & 7)) << 3));
                o[0][j] = __builtin_amdgcn_mfma_f32_16x16x32_bf16(pf[0][0], vfa, o[0][j], 0, 0, 0);
                o[0][j] = __builtin_amdgcn_mfma_f32_16x16x32_bf16(pf[0][1], vfb, o[0][j], 0, 0, 0);
                o[1][j] = __builtin_amdgcn_mfma_f32_16x16x32_bf16(pf[1][0], vfa, o[1][j], 0, 0, 0);
                o[1][j] = __builtin_amdgcn_mfma_f32_16x16x32_bf16(pf[1][1], vfb, o[1][j], 0, 0, 0);
            }
            __builtin_amdgcn_s_setprio(0);
        }

        // final row-sum reduce + normalize + write O[b*2048+q][h*128+d]
        for (int d = 1; d < 16; d <<= 1)
            for (int f = 0; f < 2; ++f)
                for (int r = 0; r < 4; ++r)
                    l2[f][r] += __shfl_xor(l2[f][r], d);
        for (int f = 0; f < 2; ++f) {
            float inv[4];
            for (int r = 0; r < 4; ++r) inv[r] = 1.f / l2[f][r];
            bf16* Ob = O + ((size_t)b * 2048 + qa + f * 16) * 2048 + h * 128;
            for (int j = 0; j < 8; ++j)
                for (int r = 0; r < 4; ++r)
                    Ob[(size_t)(lg * 4 + r) * 2048 + j * 16 + l15] = (bf16)(o[f][j][r] * inv[r]);
        }
    }
}

extern "C" void kernel_launch(void* const* d_in, const int* in_sizes, int n_in,
                              void* d_out, int out_size, void* d_ws, size_t ws_size,
                              hipStream_t stream) {
    const float* x     = (const float*)d_in[0];   // [8192][2048] f32
    const float* wqkv  = (const float*)d_in[1];   // [2048][6144] f32
    const float* wproj = (const float*)d_in[2];   // [2048][2048] f32
    float* out = (float*)d_out;                   // [8192][2048] f32

    char* ws = (char*)d_ws;
    bf16* xb     = (bf16*)(ws);                                   // 33554432 B
    bf16* wqkvT  = (bf16*)(ws + 33554432);                        // 25165824 B
    bf16* wprojT = (bf16*)(ws + 33554432 + 25165824);             //  8388608 B
    bf16* QKV    = (bf16*)(ws + 33554432 + 25165824 + 8388608);   // 100663296 B
    bf16* Obuf   = xb;  // aliases xb — x dead after GEMM1

    prep_all<<<dim3(32768), 256, 0, stream>>>(x, xb, wqkv, wqkvT, wproj, wprojT);
    gemm256_bt<bf16><<<dim3(24, 32), 1024, 0, stream>>>(xb, wqkvT, QKV, 8192, 6144, 2048);
    attn_fwd<<<dim3(8, 64), 256, 0, stream>>>(QKV, Obuf);
    gemm256_bt<float><<<dim3(8, 32), 1024, 0, stream>>>(Obuf, wprojT, out, 8192, 2048, 2048);
}

// Round 24
// 450.360 us; speedup vs baseline: 1.0531x; 1.0531x over previous
//
#include <hip/hip_runtime.h>
#include <hip/hip_bf16.h>
#include <math.h>

typedef __bf16 bf16;
typedef __bf16 bf16x8 __attribute__((ext_vector_type(8)));
typedef float f32x4 __attribute__((ext_vector_type(4)));

#define AS1(p) ((const __attribute__((address_space(1))) void*)(p))
#define AS3(p) ((__attribute__((address_space(3))) void*)(p))

__device__ __forceinline__ void gl_lds16(const bf16* g, bf16* l) {
    __builtin_amdgcn_global_load_lds(AS1(g), AS3(l), 16, 0, 0);
}

// ---------------- fused prep: cast x, transpose+cast wqkv, transpose+cast wproj -------
__device__ __forceinline__ void transpose_body(const float* __restrict__ in,
                                               bf16* __restrict__ out,
                                               int R, int Cc, int bx, int by, int t) {
    __shared__ float tile[32][33];
    const int r0 = by * 32, c0 = bx * 32;
    for (int i = 0; i < 4; ++i) {
        int idx = t + i * 256;
        int r = idx >> 5, c = idx & 31;
        tile[r][c] = in[(size_t)(r0 + r) * Cc + c0 + c];
    }
    __syncthreads();
    for (int i = 0; i < 4; ++i) {
        int idx = t + i * 256;
        int r = idx >> 5, c = idx & 31;
        out[(size_t)(c0 + r) * R + r0 + c] = (bf16)tile[c][r];
    }
}

__global__ __launch_bounds__(256) void prep_all(const float* __restrict__ x, bf16* __restrict__ xb,
                                                const float* __restrict__ wqkv, bf16* __restrict__ wqkvT,
                                                const float* __restrict__ wproj, bf16* __restrict__ wprojT) {
    const int t = threadIdx.x;
    const int bid = blockIdx.x;
    if (bid < 16384) {
        long i = ((long)bid * 256 + t) * 4;
        float4 v = *(const float4*)(x + i);
        xb[i + 0] = (bf16)v.x;
        xb[i + 1] = (bf16)v.y;
        xb[i + 2] = (bf16)v.z;
        xb[i + 3] = (bf16)v.w;
    } else if (bid < 28672) {
        int idx = bid - 16384;                       // 192 x 64 tiles
        transpose_body(wqkv, wqkvT, 2048, 6144, idx % 192, idx / 192, t);
    } else {
        int idx = bid - 28672;                       // 64 x 64 tiles
        transpose_body(wproj, wprojT, 2048, 2048, idx % 64, idx / 64, t);
    }
}

// ---------------- GEMM 256x256, BK=64, 16 waves (4x4), double-buffered LDS -----------
// ROUND-20/22 KNOWN-BEST (184us, MfmaUtil 51%): 16 waves of 64x64, 4 waves/SIMD
// overlap the LDS pipe (~3070 cy/iter) with the MFMA pipe (~2480 cy/iter). This is
// the local optimum of the template family: BK=32 (r23: 2x barriers > TLP gain),
// 8 waves/SIMD (r21: spill), 8x128-out waves (r8/r9), 32x32 MFMA (r14: conflicts),
// counted-vmcnt (r11), 4-phase (r12) ALL measured and regressed.
// LDS tiles XOR-chunk-swizzled (chunk ^ (row&7)); bn-supertile order (nbx % 8 == 0).
template <typename OT>
__global__ __launch_bounds__(1024, 4) void gemm256_bt(const bf16* __restrict__ A,
                                                      const bf16* __restrict__ BT,
                                                      OT* __restrict__ C,
                                                      int M, int N, int K) {
    __shared__ bf16 lds[2][2][256 * 64];  // [buf][A/B][row*64 + col]
    const int t = threadIdx.x;
    const int lane = t & 63;
    const int w = t >> 6;
    const int wr = w >> 2, wc = w & 3;      // 4 x 4 wave grid; wave out = 64x64
    const int l15 = lane & 15, lg = lane >> 4;

    // supertile remap: 8 consecutive bn columns x all bm per group
    const int nbx = gridDim.x, nby = gridDim.y;
    const int orig = blockIdx.y * nbx + blockIdx.x;
    const int span = nby * 8;
    const int grp = orig / span, rem = orig % span;
    const int bm = rem >> 3, bn = grp * 8 + (rem & 7);

    const bf16* Ab = A + (size_t)bm * 256 * K;
    const bf16* Bb = BT + (size_t)bn * 256 * K;

    f32x4 acc[4][4] = {};

    const int nk = K / 64;
    int cur = 0;
    // prologue: stage K-tile 0 into buf0 (2048 chunks of 16B per operand, 2/thread)
    for (int j = 0; j < 2; ++j) {
        int cid = j * 1024 + t;
        int r = cid >> 3, c = cid & 7;
        int src = (c ^ (r & 7)) << 3;
        gl_lds16(Ab + (size_t)r * K + src, &lds[0][0][cid * 8]);
        gl_lds16(Bb + (size_t)r * K + src, &lds[0][1][cid * 8]);
    }

    for (int kt = 0; kt < nk; ++kt) {
        __syncthreads();  // buf[cur] staged loads landed; all prior ds_reads complete

        if (kt + 1 < nk) {  // issue prefetch AFTER barrier -> flies a full iteration
            const int k0 = (kt + 1) * 64;
            for (int j = 0; j < 2; ++j) {
                int cid = j * 1024 + t;
                int r = cid >> 3, c = cid & 7;
                int src = (c ^ (r & 7)) << 3;
                gl_lds16(Ab + (size_t)r * K + k0 + src, &lds[cur ^ 1][0][cid * 8]);
                gl_lds16(Bb + (size_t)r * K + k0 + src, &lds[cur ^ 1][1][cid * 8]);
            }
        }

        const bf16* lA = &lds[cur][0][0];
        const bf16* lB = &lds[cur][1][0];
        #pragma unroll
        for (int kk = 0; kk < 2; ++kk) {
            bf16x8 bfr[4];
            #pragma unroll
            for (int n = 0; n < 4; ++n) {
                int R = wc * 64 + n * 16 + l15;
                bfr[n] = *(const bf16x8*)(lB + R * 64 + (((kk * 4 + lg) ^ (R & 7)) << 3));
            }
            // software-pipelined A reads: issue m+1's read during m's MFMAs
            int R0 = wr * 64 + l15;
            bf16x8 a = *(const bf16x8*)(lA + R0 * 64 + (((kk * 4 + lg) ^ (R0 & 7)) << 3));
            __builtin_amdgcn_s_setprio(1);
            #pragma unroll
            for (int m = 0; m < 4; ++m) {
                bf16x8 c0 = a;
                if (m + 1 < 4) {
                    int Rn = wr * 64 + (m + 1) * 16 + l15;
                    a = *(const bf16x8*)(lA + Rn * 64 + (((kk * 4 + lg) ^ (Rn & 7)) << 3));
                }
                #pragma unroll
                for (int n = 0; n < 4; ++n)
                    acc[m][n] = __builtin_amdgcn_mfma_f32_16x16x32_bf16(c0, bfr[n], acc[m][n], 0, 0, 0);
            }
            __builtin_amdgcn_s_setprio(0);
        }
        cur ^= 1;
    }

    for (int m = 0; m < 4; ++m)
        for (int n = 0; n < 4; ++n) {
            int row = bm * 256 + wr * 64 + m * 16 + lg * 4;
            int col = bn * 256 + wc * 64 + n * 16 + l15;
            for (int r = 0; r < 4; ++r)
                C[(size_t)(row + r) * N + col] = (OT)acc[m][n][r];
        }
}

// ---------------- causal flash attention ----------------
// Round-20 config (best): single-buffered lK (3 blocks/CU), early V(t+1)->regs at
// top of tile, K(t+1) gl_lds after barrier B. lK/lVt XOR-chunk-swizzled; lP stride
// 68; exp2-domain softmax, defer-max, Q-prescaled, causal fast-path, balanced pairs.
__global__ __launch_bounds__(256, 2) void attn_fwd(const bf16* __restrict__ QKV,
                                                   bf16* __restrict__ O) {
    __shared__ bf16 lK[64 * 128];    // [64 kv][16 chunks of 8], chunk ^ (row&7)
    __shared__ bf16 lVt[128 * 64];   // V^T [128 hd][8 chunks of 8], chunk ^ (row&7)
    __shared__ bf16 lP[4][32 * 68];  // per-wave P [32 q][64 kv], row stride 68

    const int t = threadIdx.x, lane = t & 63, w = t >> 6;
    const int l15 = lane & 15, lg = lane >> 4;
    const int bh = blockIdx.y;
    const int b = bh >> 4, h = bh & 15;
    const size_t rs = 6144;

    const bf16* Qb = QKV + (size_t)b * 2048 * rs + h * 128;
    const bf16* Kb = Qb + 2048;
    const bf16* Vb = Qb + 4096;

    const float C = 0.12751705f;  // 128^-0.5 * log2(e)
    const int kvp = t & 31;         // kv-pair id for V staging
    const int hd0 = (t >> 5) * 16;  // hd group base for V staging

    for (int half = 0; half < 2; ++half) {
        const int qt = half == 0 ? (15 - (int)blockIdx.x) : (int)blockIdx.x;
        const int q0 = qt * 128;
        const int qa = q0 + w * 32;  // wave's q rows [qa, qa+32)

        // Q fragments, PRESCALED by C (exp2-domain)
        bf16x8 qf[2][4];
        for (int f = 0; f < 2; ++f)
            for (int kk = 0; kk < 4; ++kk) {
                bf16x8 q = *(const bf16x8*)(Qb + (size_t)(qa + f * 16 + l15) * rs + kk * 32 + lg * 8);
                for (int e = 0; e < 8; ++e) q[e] = (bf16)((float)q[e] * C);
                qf[f][kk] = q;
            }

        f32x4 o[2][8] = {};
        float m2[2][4], l2[2][4];
        for (int f = 0; f < 2; ++f)
            for (int r = 0; r < 4; ++r) { m2[f][r] = -1e30f; l2[f][r] = 0.f; }

        const int nt = q0 / 64 + 2;

        // prologue: stage K(0) via gl_lds, V(0) -> regs
        for (int j = 0; j < 4; ++j) {
            int c = j * 256 + t;
            int r = c >> 4, cc = c & 15;
            gl_lds16(Kb + (size_t)r * rs + ((cc ^ (r & 7)) << 3), lK + (size_t)c * 8);
        }
        bf16x8 vr0, vr1, vr2, vr3;
        {
            const bf16* p = Vb + (size_t)(2 * kvp) * rs + hd0;
            vr0 = *(const bf16x8*)(p);
            vr1 = *(const bf16x8*)(p + rs);
            vr2 = *(const bf16x8*)(p + 8);
            vr3 = *(const bf16x8*)(p + rs + 8);
        }

        for (int kt = 0; kt < nt; ++kt) {
            const int kv0 = kt * 64;
            __syncthreads();  // barrier A: drains vmcnt -> K(kt) in LDS, V(kt) in regs

            // write V^T (swizzled chunks), packed u32 -- frees vr0-3
            for (int e = 0; e < 8; ++e) {
                union { bf16 h2[2]; unsigned u; } p0, p1;
                p0.h2[0] = vr0[e]; p0.h2[1] = vr1[e];
                p1.h2[0] = vr2[e]; p1.h2[1] = vr3[e];
                int r0 = hd0 + e, r1 = hd0 + 8 + e;
                *(unsigned*)(lVt + r0 * 64 + (((kvp >> 2) ^ (r0 & 7)) << 3) + ((kvp & 3) << 1)) = p0.u;
                *(unsigned*)(lVt + r1 * 64 + (((kvp >> 2) ^ (r1 & 7)) << 3) + ((kvp & 3) << 1)) = p1.u;
            }

            // EARLY V(t+1)->regs: zero LDS cost, flies the whole tile (L3 latency cover)
            if (kt + 1 < nt) {
                const bf16* p = Vb + (size_t)(kv0 + 64 + 2 * kvp) * rs + hd0;
                vr0 = *(const bf16x8*)(p);
                vr1 = *(const bf16x8*)(p + rs);
                vr2 = *(const bf16x8*)(p + 8);
                vr3 = *(const bf16x8*)(p + rs + 8);
            }

            // S = Q K^T  (32 q x 64 kv); K frags reused for both q-frags
            f32x4 s[2][4] = {};
            __builtin_amdgcn_s_setprio(1);
            for (int n = 0; n < 4; ++n) {
                int row = n * 16 + l15;
                for (int kk = 0; kk < 4; ++kk) {
                    bf16x8 kf = *(const bf16x8*)(lK + row * 128 + (((kk * 4 + lg) ^ (row & 7)) << 3));
                    s[0][n] = __builtin_amdgcn_mfma_f32_16x16x32_bf16(qf[0][kk], kf, s[0][n], 0, 0, 0);
                    s[1][n] = __builtin_amdgcn_mfma_f32_16x16x32_bf16(qf[1][kk], kf, s[1][n], 0, 0, 0);
                }
            }
            __builtin_amdgcn_s_setprio(0);

            // causal mask (wave-uniform fast path: tile fully below diagonal)
            float pv[2][4][4];
            if (kv0 + 63 <= qa) {
                for (int f = 0; f < 2; ++f)
                    for (int n = 0; n < 4; ++n)
                        for (int r = 0; r < 4; ++r)
                            pv[f][n][r] = s[f][n][r];
            } else {
                for (int f = 0; f < 2; ++f)
                    for (int n = 0; n < 4; ++n)
                        for (int r = 0; r < 4; ++r) {
                            int qg = qa + f * 16 + lg * 4 + r;
                            int kg = kv0 + n * 16 + l15;
                            pv[f][n][r] = (kg <= qg) ? s[f][n][r] : -1e30f;
                        }
            }
            float pmax[2][4];
            for (int f = 0; f < 2; ++f)
                for (int r = 0; r < 4; ++r)
                    pmax[f][r] = fmaxf(fmaxf(pv[f][0][r], pv[f][1][r]), fmaxf(pv[f][2][r], pv[f][3][r]));
            for (int d = 1; d < 16; d <<= 1)
                for (int f = 0; f < 2; ++f)
                    for (int r = 0; r < 4; ++r)
                        pmax[f][r] = fmaxf(pmax[f][r], __shfl_xor(pmax[f][r], d));
            // defer-max: only rescale when max grew by > 8 (log2 domain)
            bool need = false;
            for (int f = 0; f < 2; ++f)
                for (int r = 0; r < 4; ++r)
                    need = need || (pmax[f][r] > m2[f][r] + 8.f);
            if (__any(need ? 1 : 0)) {
                for (int f = 0; f < 2; ++f)
                    for (int r = 0; r < 4; ++r) {
                        float mn = fmaxf(m2[f][r], pmax[f][r]);
                        float al = exp2f(m2[f][r] - mn);
                        m2[f][r] = mn;
                        l2[f][r] *= al;
                        for (int j = 0; j < 8; ++j) o[f][j][r] *= al;
                    }
            }
            for (int f = 0; f < 2; ++f)
                for (int n = 0; n < 4; ++n)
                    for (int r = 0; r < 4; ++r) {
                        float p = exp2f(pv[f][n][r] - m2[f][r]);
                        l2[f][r] += p;
                        lP[w][(f * 16 + lg * 4 + r) * 68 + n * 16 + l15] = (bf16)p;
                    }
            bf16x8 pf[2][2];
            for (int f = 0; f < 2; ++f) {
                pf[f][0] = *(const bf16x8*)(&lP[w][(f * 16 + l15) * 68 + lg * 8]);
                pf[f][1] = *(const bf16x8*)(&lP[w][(f * 16 + l15) * 68 + 32 + lg * 8]);
            }

            __syncthreads();  // barrier B: lVt fully written; lK reads done by all waves

            // K(t+1) -> lK via gl_lds (after barrier B: all lK reads done); flies during PV
            if (kt + 1 < nt) {
                const int nk2 = kv0 + 64;
                for (int j = 0; j < 4; ++j) {
                    int c = j * 256 + t;
                    int r = c >> 4, cc = c & 15;
                    gl_lds16(Kb + (size_t)(nk2 + r) * rs + ((cc ^ (r & 7)) << 3), lK + (size_t)c * 8);
                }
            }

            // O += P V ; V frags reused for both q-frags
            __builtin_amdgcn_s_setprio(1);
            for (int j = 0; j < 8; ++j) {
                int R = j * 16 + l15;
                bf16x8 vfa = *(const bf16x8*)(lVt + R * 64 + ((lg ^ (R & 7)) << 3));
                bf16x8 vfb = *(const bf16x8*)(lVt + R * 64 + (((4 + lg) ^ (R & 7)) << 3));
                o[0][j] = __builtin_amdgcn_mfma_f32_16x16x32_bf16(pf[0][0], vfa, o[0][j], 0, 0, 0);
                o[0][j] = __builtin_amdgcn_mfma_f32_16x16x32_bf16(pf[0][1], vfb, o[0][j], 0, 0, 0);
                o[1][j] = __builtin_amdgcn_mfma_f32_16x16x32_bf16(pf[1][0], vfa, o[1][j], 0, 0, 0);
                o[1][j] = __builtin_amdgcn_mfma_f32_16x16x32_bf16(pf[1][1], vfb, o[1][j], 0, 0, 0);
            }
            __builtin_amdgcn_s_setprio(0);
        }

        // final row-sum reduce + normalize + write O[b*2048+q][h*128+d]
        for (int d = 1; d < 16; d <<= 1)
            for (int f = 0; f < 2; ++f)
                for (int r = 0; r < 4; ++r)
                    l2[f][r] += __shfl_xor(l2[f][r], d);
        for (int f = 0; f < 2; ++f) {
            float inv[4];
            for (int r = 0; r < 4; ++r) inv[r] = 1.f / l2[f][r];
            bf16* Ob = O + ((size_t)b * 2048 + qa + f * 16) * 2048 + h * 128;
            for (int j = 0; j < 8; ++j)
                for (int r = 0; r < 4; ++r)
                    Ob[(size_t)(lg * 4 + r) * 2048 + j * 16 + l15] = (bf16)(o[f][j][r] * inv[r]);
        }
    }
}

extern "C" void kernel_launch(void* const* d_in, const int* in_sizes, int n_in,
                              void* d_out, int out_size, void* d_ws, size_t ws_size,
                              hipStream_t stream) {
    const float* x     = (const float*)d_in[0];   // [8192][2048] f32
    const float* wqkv  = (const float*)d_in[1];   // [2048][6144] f32
    const float* wproj = (const float*)d_in[2];   // [2048][2048] f32
    float* out = (float*)d_out;                   // [8192][2048] f32

    char* ws = (char*)d_ws;
    bf16* xb     = (bf16*)(ws);                                   // 33554432 B
    bf16* wqkvT  = (bf16*)(ws + 33554432);                        // 25165824 B
    bf16* wprojT = (bf16*)(ws + 33554432 + 25165824);             //  8388608 B
    bf16* QKV    = (bf16*)(ws + 33554432 + 25165824 + 8388608);   // 100663296 B
    bf16* Obuf   = xb;  // aliases xb — x dead after GEMM1

    prep_all<<<dim3(32768), 256, 0, stream>>>(x, xb, wqkv, wqkvT, wproj, wprojT);
    gemm256_bt<bf16><<<dim3(24, 32), 1024, 0, stream>>>(xb, wqkvT, QKV, 8192, 6144, 2048);
    attn_fwd<<<dim3(8, 64), 256, 0, stream>>>(QKV, Obuf);
    gemm256_bt<float><<<dim3(8, 32), 1024, 0, stream>>>(Obuf, wprojT, out, 8192, 2048, 2048);
}